// Round 5
// baseline (482.125 us; speedup 1.0000x reference)
//
#include <hip/hip_runtime.h>
#include <hip/hip_bf16.h>

// Problem constants
#define BB 512
#define LL 1024
#define AA 13
#define NBP 5
#define NTOT (BB * LL)
#define EPSV 1e-5f

// ws layout (floats)
#define WS_F    192      // 10: F[nn] = sum over half-l of flw
#define WS_PART 256      // 256 blocks * 40 moment partials

// ---- DPP wave64 sum: result valid in lane 63 (VALU pipe, no LDS) ----
template<int CTRL, int RM, bool BC>
__device__ __forceinline__ float dppadd(float v) {
    int t = __builtin_amdgcn_update_dpp(0, __float_as_int(v), CTRL, RM, 0xf, BC);
    return v + __int_as_float(t);
}
__device__ __forceinline__ float wave_sum(float v) {
    v = dppadd<0x111, 0xf, true >(v);   // row_shr:1
    v = dppadd<0x112, 0xf, true >(v);   // row_shr:2
    v = dppadd<0x114, 0xf, true >(v);   // row_shr:4
    v = dppadd<0x118, 0xf, true >(v);   // row_shr:8
    v = dppadd<0x142, 0xa, false>(v);   // row_bcast15
    v = dppadd<0x143, 0xc, false>(v);   // row_bcast31 -> lane63 total
    return v;
}

// ---------------- Kernel 1: depthwise-output moment partials + flw half-row sums ----------------
__global__ __launch_bounds__(256) void k_moments(
    const float* __restrict__ src,
    const float* __restrict__ dw1,
    const float* __restrict__ dw2,
    const float* __restrict__ flw,
    float* __restrict__ ws)
{
    __shared__ float red[4][40];
    __shared__ float fred[4];
    int tid = threadIdx.x;
    int gid = blockIdx.x * 256 + tid;
    int b = gid >> 7, L0 = (gid & 127) << 3;     // 8-wide strip per thread
    const float* sb = src + b * (5 * LL);

    float w1[5][5], w2[5][3];
#pragma unroll
    for (int c = 0; c < 5; c++) {
#pragma unroll
        for (int t = 0; t < 5; t++) w1[c][t] = dw1[c*5+t];
#pragma unroll
        for (int t = 0; t < 3; t++) w2[c][t] = dw2[c*3+t];
    }

    // x[c5][m] covers l = L0-4 .. L0+11
    float x[5][16];
#pragma unroll
    for (int c5 = 0; c5 < 5; c5++) {
        const float* sp = sb + c5 * LL;
        float4 xa = (L0 >= 4)    ? *(const float4*)(sp + L0 - 4) : make_float4(0,0,0,0);
        float4 xb = *(const float4*)(sp + L0);
        float4 xc = *(const float4*)(sp + L0 + 4);
        float4 xd = (L0 <= 1012) ? *(const float4*)(sp + L0 + 8) : make_float4(0,0,0,0);
        x[c5][0]=xa.x; x[c5][1]=xa.y; x[c5][2]=xa.z; x[c5][3]=xa.w;
        x[c5][4]=xb.x; x[c5][5]=xb.y; x[c5][6]=xb.z; x[c5][7]=xb.w;
        x[c5][8]=xc.x; x[c5][9]=xc.y; x[c5][10]=xc.z; x[c5][11]=xc.w;
        x[c5][12]=xd.x; x[c5][13]=xd.y; x[c5][14]=xd.z; x[c5][15]=xd.w;
    }

    float acc[40];
#pragma unroll
    for (int k = 0; k < 40; k++) acc[k] = 0.f;

#pragma unroll
    for (int k = 0; k < 8; k++) {              // l = L0 + k
        float d1[5], d2[5];
#pragma unroll
        for (int c5 = 0; c5 < 5; c5++) {
            d1[c5] = w1[c5][0]*x[c5][k+2] + w1[c5][1]*x[c5][k+3] + w1[c5][2]*x[c5][k+4]
                   + w1[c5][3]*x[c5][k+5] + w1[c5][4]*x[c5][k+6];
            d2[c5] = w2[c5][0]*x[c5][k+3] + w2[c5][1]*x[c5][k+4] + w2[c5][2]*x[c5][k+5];
        }
#pragma unroll
        for (int j = 0; j < 5; j++) { acc[j] += d1[j]; acc[20+j] += d2[j]; }
#pragma unroll
        for (int j = 0; j < 5; j++)
#pragma unroll
            for (int kk = j; kk < 5; kk++) {
                int idx = j*(11-j)/2 + (kk - j);
                acc[5+idx]  += d1[j]*d1[kk];
                acc[25+idx] += d2[j]*d2[kk];
            }
    }

    int lane = tid & 63, wv = tid >> 6;
#pragma unroll
    for (int k = 0; k < 40; k++) acc[k] = wave_sum(acc[k]);
    if (lane == 63) {
#pragma unroll
        for (int k = 0; k < 40; k++) red[wv][k] = acc[k];
    }
    __syncthreads();
    if (tid < 40) {
        // per-block partial, plain store (no atomics, no memset needed)
        ws[WS_PART + blockIdx.x * 40 + tid] =
            red[0][tid] + red[1][tid] + red[2][tid] + red[3][tid];
    }

    // F[nn] = sum of one flw half-row; blocks 0..9 own one row each
    if (blockIdx.x < 10) {
        int nn = blockIdx.x;
        int n = nn < 5 ? nn : nn - 5;
        int off = nn < 5 ? 0 : LL;
        float4 v = *(const float4*)(flw + n * (2*LL) + off + tid * 4);
        float s = wave_sum(v.x + v.y + v.z + v.w);
        if (lane == 63) fred[wv] = s;
        __syncthreads();
        if (tid == 0) ws[WS_F + nn] = fred[0] + fred[1] + fred[2] + fred[3];
    }
}

// ---------------- Kernel 2 (fused): BN-prep prologue + main contraction + PQ + out ----------------
__global__ __launch_bounds__(512, 4) void k_fused(
    const float* __restrict__ src,
    const float* __restrict__ dw1,
    const float* __restrict__ dw2,
    const float* __restrict__ pw1, const float* __restrict__ pw2,
    const float* __restrict__ g1,  const float* __restrict__ be1,
    const float* __restrict__ g2,  const float* __restrict__ be2,
    const float* __restrict__ r1w, const float* __restrict__ r2w,
    const float* __restrict__ r1b, const float* __restrict__ r2b,
    const float* __restrict__ flw,
    const float* __restrict__ ll1w,
    const float* __restrict__ ll1b,
    const float* __restrict__ flb,
    const float* __restrict__ ws,
    float* __restrict__ out)
{
    __shared__ __align__(16) float srcS[5][1040];  // i = l + 8; halo zeros at i=4..7, 1032..1035
    __shared__ __align__(16) float constS[64][16]; // packed per-channel consts
    __shared__ __align__(16) float SLds[64][12];
    __shared__ float momS[40];
    __shared__ float llT[832];                     // ll1w transposed: [c*13 + a]
    __shared__ float PQ[130];

    int tid = threadIdx.x, b = blockIdx.x;
    int lane = tid & 63;
    int gu = __builtin_amdgcn_readfirstlane(tid >> 6);   // wave 0..7
    int br = gu >> 2;                                     // waves 0-3 branch1, 4-7 branch2

    const float* srcB = src + b * (5 * LL);

    // ---- stage src (whole L, 5 channels) ----
    for (int idx = tid; idx < 5 * 256; idx += 512) {
        int c5 = idx >> 8, q = idx & 255;
        float4 v = *(const float4*)(srcB + (c5 << 10) + (q << 2));
        *(float4*)&srcS[c5][(q << 2) + 8] = v;
    }
    if (tid < 40) {   // halo zeros: i = 4..7 and 1032..1035 per channel
        int c5 = tid >> 3, j = tid & 7;
        int i = (j < 4) ? (4 + j) : (1028 + j);
        srcS[c5][i] = 0.f;
    }
    // ---- stage ll1w transposed ----
    for (int idx = tid; idx < 832; idx += 512) {
        int cc = idx / 13, a = idx - cc * 13;
        llT[idx] = ll1w[a * 64 + cc];
    }
    // ---- reduce moment partials: 40 values x 256 partials ----
    if (tid < 320) {
        int k = tid >> 3, sub = tid & 7;
        float v = 0.f;
#pragma unroll 8
        for (int t2 = 0; t2 < 32; t2++) v += ws[WS_PART + (sub + (t2 << 3)) * 40 + k];
        v += __shfl_xor(v, 1, 64);
        v += __shfl_xor(v, 2, 64);
        v += __shfl_xor(v, 4, 64);
        if (sub == 0) momS[k] = v;
    }
    __syncthreads();
    // ---- BN finalize -> packed consts in LDS (threads 0..63 = channels) ----
    if (tid < 64) {
        int brc = tid >> 5, o = tid & 31;
        const float invN = 1.0f / (float)NTOT;
        const float* pw = brc ? pw2 : pw1;
        const float* rw = brc ? r2w : r1w;
        const float* s  = momS + (brc ? 20 : 0);
        const float* M  = momS + (brc ? 25 : 5);
        float pwv[5], rwv[5], md[5];
#pragma unroll
        for (int j = 0; j < 5; j++) { pwv[j] = pw[o*5+j]; rwv[j] = rw[o*5+j]; md[j] = s[j] * invN; }
        float meanY = 0.f;
#pragma unroll
        for (int j = 0; j < 5; j++) meanY += pwv[j] * md[j];
        float ey2 = 0.f;
#pragma unroll
        for (int j = 0; j < 5; j++)
#pragma unroll
            for (int k = 0; k < 5; k++) {
                int lo = j < k ? j : k, hi = j < k ? k : j;
                int idx = lo*(11-lo)/2 + (hi - lo);
                ey2 += pwv[j] * pwv[k] * (M[idx] * invN);
            }
        float varY = ey2 - meanY * meanY;
        if (varY < 0.f) varY = 0.f;
        float gg = brc ? g2[o] : g1[o];
        float bb = brc ? be2[o] : be1[o];
        float rb = brc ? r2b[o] : r1b[o];
        float sc = gg * rsqrtf(varY + EPSV);
        float sh = bb - meanY * sc;
        float* dst = &constS[tid][0];
        dst[0] = pwv[0]*sc; dst[1] = pwv[1]*sc; dst[2] = pwv[2]*sc; dst[3] = pwv[3]*sc;
        dst[4] = pwv[4]*sc; dst[5] = sh;        dst[6] = rb;        dst[7] = 0.f;
        dst[8] = rwv[0];    dst[9] = rwv[1];    dst[10] = rwv[2];   dst[11] = rwv[3];
        dst[12] = rwv[4];   dst[13] = 0.f;      dst[14] = 0.f;      dst[15] = 0.f;
    }
    __syncthreads();

    // ---- depthwise taps (wave-uniform -> scalar regs) ----
    float wdw[5][5];  // br1: 5 taps; br2: only [1..3] used
    if (br == 0) {
#pragma unroll
        for (int c5 = 0; c5 < 5; c5++)
#pragma unroll
            for (int t = 0; t < 5; t++) wdw[c5][t] = dw1[c5*5+t];
    } else {
#pragma unroll
        for (int c5 = 0; c5 < 5; c5++) {
            wdw[c5][0] = 0.f;
            wdw[c5][1] = dw2[c5*3+0]; wdw[c5][2] = dw2[c5*3+1]; wdw[c5][3] = dw2[c5*3+2];
            wdw[c5][4] = 0.f;
        }
    }

    float acc[80];
#pragma unroll
    for (int k = 0; k < 80; k++) acc[k] = 0.f;
    int c0 = gu << 3;

#pragma unroll 1
    for (int p = 0; p < 4; p++) {
        int l0 = (p << 8) + (lane << 2);
        // flw for these 4 l's: scalar array, constant indices everywhere
        float fwv[10][4];
#pragma unroll
        for (int nn = 0; nn < 10; nn++) {
            int n = nn < 5 ? nn : nn - 5;
            int off = nn < 5 ? 0 : LL;
            float4 t4 = *(const float4*)(flw + n * (2*LL) + off + l0);
            fwv[nn][0] = t4.x; fwv[nn][1] = t4.y; fwv[nn][2] = t4.z; fwv[nn][3] = t4.w;
        }
        // src window: 3 aligned b128 reads per channel (conflict-free stride-4)
        float dv[5][4], sv[5][4];
#pragma unroll
        for (int c5 = 0; c5 < 5; c5++) {
            int i0 = l0 + 8;
            float4 xa = *(const float4*)&srcS[c5][i0 - 4];
            float4 xb = *(const float4*)&srcS[c5][i0];
            float4 xc = *(const float4*)&srcS[c5][i0 + 4];
            float xx[12] = {xa.x, xa.y, xa.z, xa.w, xb.x, xb.y, xb.z, xb.w, xc.x, xc.y, xc.z, xc.w};
            sv[c5][0] = xb.x; sv[c5][1] = xb.y; sv[c5][2] = xb.z; sv[c5][3] = xb.w;
            if (br == 0) {
#pragma unroll
                for (int q = 0; q < 4; q++)
                    dv[c5][q] = wdw[c5][0]*xx[q+2] + wdw[c5][1]*xx[q+3] + wdw[c5][2]*xx[q+4]
                              + wdw[c5][3]*xx[q+5] + wdw[c5][4]*xx[q+6];
            } else {
#pragma unroll
                for (int q = 0; q < 4; q++)
                    dv[c5][q] = wdw[c5][1]*xx[q+3] + wdw[c5][2]*xx[q+4] + wdw[c5][3]*xx[q+5];
            }
        }
        // 8 channels of this wave
#pragma unroll
        for (int ci = 0; ci < 8; ci++) {
            const float4 A  = *(const float4*)&constS[c0+ci][0];
            const float4 B2 = *(const float4*)&constS[c0+ci][4];
            const float4 R0 = *(const float4*)&constS[c0+ci][8];
            const float4 R1 = *(const float4*)&constS[c0+ci][12];
            float e[4];
#pragma unroll
            for (int q = 0; q < 4; q++) {
                float y = B2.y + A.x*dv[0][q] + A.y*dv[1][q] + A.z*dv[2][q]
                                + A.w*dv[3][q] + B2.x*dv[4][q];
                float r = B2.z + R0.x*sv[0][q] + R0.y*sv[1][q] + R0.z*sv[2][q]
                                + R0.w*sv[3][q] + R1.x*sv[4][q];
                e[q] = fmaxf(y, 0.f) * r;
            }
#pragma unroll
            for (int nn = 0; nn < 10; nn++) {
                acc[ci*10 + nn] += e[0]*fwv[nn][0] + e[1]*fwv[nn][1]
                                 + e[2]*fwv[nn][2] + e[3]*fwv[nn][3];
            }
        }
    }

    // ---- reduce acc over 64 lanes (DPP); lane 63 writes this wave's 8 S rows ----
#pragma unroll
    for (int k = 0; k < 80; k++) acc[k] = wave_sum(acc[k]);
    if (lane == 63) {
#pragma unroll
        for (int ci = 0; ci < 8; ci++) {
            int c = c0 + ci;
            *(float4*)&SLds[c][0] = make_float4(acc[ci*10+0], acc[ci*10+1], acc[ci*10+2], acc[ci*10+3]);
            *(float4*)&SLds[c][4] = make_float4(acc[ci*10+4], acc[ci*10+5], acc[ci*10+6], acc[ci*10+7]);
            *(float2*)&SLds[c][8] = make_float2(acc[ci*10+8], acc[ci*10+9]);
        }
    }
    __syncthreads();

    // ---- PQ[half][a][n] = sum_c llT[c][a] * S[c][half*5+n] + ll1b[a] * F[half*5+n] ----
    if (tid < 130) {
        int half = tid >= 65 ? 1 : 0;
        int q = tid - half * 65;
        int a = q / 5, n = q - a * 5;
        int col = half * 5 + n;
        float v = ll1b[a] * ws[WS_F + col];
#pragma unroll 8
        for (int cc = 0; cc < 64; cc++) v += llT[cc * 13 + a] * SLds[cc][col];
        PQ[tid] = v;
    }
    __syncthreads();

    // ---- out[b,i,j,n] = P[min,n] + Q[max,n] + flb[n] ----
    for (int idx = tid; idx < AA * AA * NBP; idx += 512) {
        int i = idx / 65;
        int rr = idx - i * 65;
        int j = rr / 5, n = rr - j * 5;
        int mn = i < j ? i : j, mx = i < j ? j : i;
        out[b * (AA * AA * NBP) + idx] = PQ[mn * 5 + n] + PQ[65 + mx * 5 + n] + flb[n];
    }
}

extern "C" void kernel_launch(void* const* d_in, const int* in_sizes, int n_in,
                              void* d_out, int out_size, void* d_ws, size_t ws_size,
                              hipStream_t stream) {
    const float* src  = (const float*)d_in[0];
    // d_in[1] = mask (unused), d_in[2] = max_atoms (unused, == 13)
    const float* dw1  = (const float*)d_in[3];
    const float* pw1  = (const float*)d_in[4];
    const float* g1   = (const float*)d_in[5];
    const float* be1  = (const float*)d_in[6];
    const float* r1w  = (const float*)d_in[7];
    const float* r1b  = (const float*)d_in[8];
    const float* dw2  = (const float*)d_in[9];
    const float* pw2  = (const float*)d_in[10];
    const float* g2   = (const float*)d_in[11];
    const float* be2  = (const float*)d_in[12];
    const float* r2w  = (const float*)d_in[13];
    const float* r2b  = (const float*)d_in[14];
    const float* ll1w = (const float*)d_in[15];
    const float* ll1b = (const float*)d_in[16];
    const float* flw  = (const float*)d_in[17];
    const float* flb  = (const float*)d_in[18];
    float* ws  = (float*)d_ws;
    float* out = (float*)d_out;

    k_moments<<<256, 256, 0, stream>>>(src, dw1, dw2, flw, ws);
    k_fused<<<BB, 512, 0, stream>>>(src, dw1, dw2, pw1, pw2, g1, be1, g2, be2,
                                    r1w, r2w, r1b, r2b, flw, ll1w, ll1b, flb, ws, out);
}

// Round 6
// 262.036 us; speedup vs baseline: 1.8399x; 1.8399x over previous
//
#include <hip/hip_runtime.h>
#include <hip/hip_bf16.h>

// Problem constants
#define BB 512
#define LL 1024
#define AA 13
#define NBP 5
#define NTOT (BB * LL)
#define EPSV 1e-5f

// ws layout (floats)
#define WS_F    192      // 10: F[nn] = sum over half-l of flw
#define WS_PART 256      // 256 blocks * 40 moment partials

// ---- DPP wave64 sum: result valid in lane 63 (VALU pipe, no LDS) ----
template<int CTRL, int RM, bool BC>
__device__ __forceinline__ float dppadd(float v) {
    int t = __builtin_amdgcn_update_dpp(0, __float_as_int(v), CTRL, RM, 0xf, BC);
    return v + __int_as_float(t);
}
__device__ __forceinline__ float wave_sum(float v) {
    v = dppadd<0x111, 0xf, true >(v);   // row_shr:1
    v = dppadd<0x112, 0xf, true >(v);   // row_shr:2
    v = dppadd<0x114, 0xf, true >(v);   // row_shr:4
    v = dppadd<0x118, 0xf, true >(v);   // row_shr:8
    v = dppadd<0x142, 0xa, false>(v);   // row_bcast15
    v = dppadd<0x143, 0xc, false>(v);   // row_bcast31 -> lane63 total
    return v;
}

// ---------------- Kernel 1: depthwise-output moment partials + flw half-row sums ----------------
__global__ __launch_bounds__(256) void k_moments(
    const float* __restrict__ src,
    const float* __restrict__ dw1,
    const float* __restrict__ dw2,
    const float* __restrict__ flw,
    float* __restrict__ ws)
{
    __shared__ float red[4][40];
    __shared__ float fred[4];
    int tid = threadIdx.x;
    int gid = blockIdx.x * 256 + tid;
    int b = gid >> 7, L0 = (gid & 127) << 3;     // 8-wide strip per thread
    const float* sb = src + b * (5 * LL);

    float w1[5][5], w2[5][3];
#pragma unroll
    for (int c = 0; c < 5; c++) {
#pragma unroll
        for (int t = 0; t < 5; t++) w1[c][t] = dw1[c*5+t];
#pragma unroll
        for (int t = 0; t < 3; t++) w2[c][t] = dw2[c*3+t];
    }

    // x[c5][m] covers l = L0-4 .. L0+11
    float x[5][16];
#pragma unroll
    for (int c5 = 0; c5 < 5; c5++) {
        const float* sp = sb + c5 * LL;
        float4 xa = (L0 >= 4)    ? *(const float4*)(sp + L0 - 4) : make_float4(0,0,0,0);
        float4 xb = *(const float4*)(sp + L0);
        float4 xc = *(const float4*)(sp + L0 + 4);
        float4 xd = (L0 <= 1012) ? *(const float4*)(sp + L0 + 8) : make_float4(0,0,0,0);
        x[c5][0]=xa.x; x[c5][1]=xa.y; x[c5][2]=xa.z; x[c5][3]=xa.w;
        x[c5][4]=xb.x; x[c5][5]=xb.y; x[c5][6]=xb.z; x[c5][7]=xb.w;
        x[c5][8]=xc.x; x[c5][9]=xc.y; x[c5][10]=xc.z; x[c5][11]=xc.w;
        x[c5][12]=xd.x; x[c5][13]=xd.y; x[c5][14]=xd.z; x[c5][15]=xd.w;
    }

    float acc[40];
#pragma unroll
    for (int k = 0; k < 40; k++) acc[k] = 0.f;

#pragma unroll
    for (int k = 0; k < 8; k++) {              // l = L0 + k
        float d1[5], d2[5];
#pragma unroll
        for (int c5 = 0; c5 < 5; c5++) {
            d1[c5] = w1[c5][0]*x[c5][k+2] + w1[c5][1]*x[c5][k+3] + w1[c5][2]*x[c5][k+4]
                   + w1[c5][3]*x[c5][k+5] + w1[c5][4]*x[c5][k+6];
            d2[c5] = w2[c5][0]*x[c5][k+3] + w2[c5][1]*x[c5][k+4] + w2[c5][2]*x[c5][k+5];
        }
#pragma unroll
        for (int j = 0; j < 5; j++) { acc[j] += d1[j]; acc[20+j] += d2[j]; }
#pragma unroll
        for (int j = 0; j < 5; j++)
#pragma unroll
            for (int kk = j; kk < 5; kk++) {
                int idx = j*(11-j)/2 + (kk - j);
                acc[5+idx]  += d1[j]*d1[kk];
                acc[25+idx] += d2[j]*d2[kk];
            }
    }

    int lane = tid & 63, wv = tid >> 6;
#pragma unroll
    for (int k = 0; k < 40; k++) acc[k] = wave_sum(acc[k]);
    if (lane == 63) {
#pragma unroll
        for (int k = 0; k < 40; k++) red[wv][k] = acc[k];
    }
    __syncthreads();
    if (tid < 40) {
        // per-block partial, plain store (no atomics, no memset needed)
        ws[WS_PART + blockIdx.x * 40 + tid] =
            red[0][tid] + red[1][tid] + red[2][tid] + red[3][tid];
    }

    // F[nn] = sum of one flw half-row; blocks 0..9 own one row each
    if (blockIdx.x < 10) {
        int nn = blockIdx.x;
        int n = nn < 5 ? nn : nn - 5;
        int off = nn < 5 ? 0 : LL;
        float4 v = *(const float4*)(flw + n * (2*LL) + off + tid * 4);
        float s = wave_sum(v.x + v.y + v.z + v.w);
        if (lane == 63) fred[wv] = s;
        __syncthreads();
        if (tid == 0) ws[WS_F + nn] = fred[0] + fred[1] + fred[2] + fred[3];
    }
}

// ---------------- Kernel 2 (fused): BN-prep prologue + main contraction + PQ + out ----------------
// NOTE: __launch_bounds__ 2nd arg observed to follow CUDA minBlocksPerCU semantics on this
// toolchain: (512,4) forced a 64-VGPR cap -> acc[80] spill storm (1.2 GB scratch traffic,
// 390 us). (512,2) = 16 waves/CU = 128-VGPR cap, matching round-4's proven no-spill alloc.
__global__ __launch_bounds__(512, 2) void k_fused(
    const float* __restrict__ src,
    const float* __restrict__ dw1,
    const float* __restrict__ dw2,
    const float* __restrict__ pw1, const float* __restrict__ pw2,
    const float* __restrict__ g1,  const float* __restrict__ be1,
    const float* __restrict__ g2,  const float* __restrict__ be2,
    const float* __restrict__ r1w, const float* __restrict__ r2w,
    const float* __restrict__ r1b, const float* __restrict__ r2b,
    const float* __restrict__ flw,
    const float* __restrict__ ll1w,
    const float* __restrict__ ll1b,
    const float* __restrict__ flb,
    const float* __restrict__ ws,
    float* __restrict__ out)
{
    __shared__ __align__(16) float srcS[5][1040];  // i = l + 8; halo zeros at i=4..7, 1032..1035
    __shared__ __align__(16) float constS[64][16]; // packed per-channel consts
    __shared__ __align__(16) float SLds[64][12];
    __shared__ float momS[40];
    __shared__ float llT[832];                     // ll1w transposed: [c*13 + a]
    __shared__ float PQ[130];

    int tid = threadIdx.x, b = blockIdx.x;
    int lane = tid & 63;
    int gu = __builtin_amdgcn_readfirstlane(tid >> 6);   // wave 0..7
    int br = gu >> 2;                                     // waves 0-3 branch1, 4-7 branch2

    const float* srcB = src + b * (5 * LL);

    // ---- stage src (whole L, 5 channels) ----
    for (int idx = tid; idx < 5 * 256; idx += 512) {
        int c5 = idx >> 8, q = idx & 255;
        float4 v = *(const float4*)(srcB + (c5 << 10) + (q << 2));
        *(float4*)&srcS[c5][(q << 2) + 8] = v;
    }
    if (tid < 40) {   // halo zeros: i = 4..7 and 1032..1035 per channel
        int c5 = tid >> 3, j = tid & 7;
        int i = (j < 4) ? (4 + j) : (1028 + j);
        srcS[c5][i] = 0.f;
    }
    // ---- stage ll1w transposed ----
    for (int idx = tid; idx < 832; idx += 512) {
        int cc = idx / 13, a = idx - cc * 13;
        llT[idx] = ll1w[a * 64 + cc];
    }
    // ---- reduce moment partials: 40 values x 256 partials ----
    if (tid < 320) {
        int k = tid >> 3, sub = tid & 7;
        float v = 0.f;
#pragma unroll 8
        for (int t2 = 0; t2 < 32; t2++) v += ws[WS_PART + (sub + (t2 << 3)) * 40 + k];
        v += __shfl_xor(v, 1, 64);
        v += __shfl_xor(v, 2, 64);
        v += __shfl_xor(v, 4, 64);
        if (sub == 0) momS[k] = v;
    }
    __syncthreads();
    // ---- BN finalize -> packed consts in LDS (threads 0..63 = channels) ----
    if (tid < 64) {
        int brc = tid >> 5, o = tid & 31;
        const float invN = 1.0f / (float)NTOT;
        const float* pw = brc ? pw2 : pw1;
        const float* rw = brc ? r2w : r1w;
        const float* s  = momS + (brc ? 20 : 0);
        const float* M  = momS + (brc ? 25 : 5);
        float pwv[5], rwv[5], md[5];
#pragma unroll
        for (int j = 0; j < 5; j++) { pwv[j] = pw[o*5+j]; rwv[j] = rw[o*5+j]; md[j] = s[j] * invN; }
        float meanY = 0.f;
#pragma unroll
        for (int j = 0; j < 5; j++) meanY += pwv[j] * md[j];
        float ey2 = 0.f;
#pragma unroll
        for (int j = 0; j < 5; j++)
#pragma unroll
            for (int k = 0; k < 5; k++) {
                int lo = j < k ? j : k, hi = j < k ? k : j;
                int idx = lo*(11-lo)/2 + (hi - lo);
                ey2 += pwv[j] * pwv[k] * (M[idx] * invN);
            }
        float varY = ey2 - meanY * meanY;
        if (varY < 0.f) varY = 0.f;
        float gg = brc ? g2[o] : g1[o];
        float bb = brc ? be2[o] : be1[o];
        float rb = brc ? r2b[o] : r1b[o];
        float sc = gg * rsqrtf(varY + EPSV);
        float sh = bb - meanY * sc;
        float* dst = &constS[tid][0];
        dst[0] = pwv[0]*sc; dst[1] = pwv[1]*sc; dst[2] = pwv[2]*sc; dst[3] = pwv[3]*sc;
        dst[4] = pwv[4]*sc; dst[5] = sh;        dst[6] = rb;        dst[7] = 0.f;
        dst[8] = rwv[0];    dst[9] = rwv[1];    dst[10] = rwv[2];   dst[11] = rwv[3];
        dst[12] = rwv[4];   dst[13] = 0.f;      dst[14] = 0.f;      dst[15] = 0.f;
    }
    __syncthreads();

    // ---- depthwise taps (wave-uniform -> scalar regs) ----
    float wdw[5][5];  // br1: 5 taps; br2: only [1..3] used
    if (br == 0) {
#pragma unroll
        for (int c5 = 0; c5 < 5; c5++)
#pragma unroll
            for (int t = 0; t < 5; t++) wdw[c5][t] = dw1[c5*5+t];
    } else {
#pragma unroll
        for (int c5 = 0; c5 < 5; c5++) {
            wdw[c5][0] = 0.f;
            wdw[c5][1] = dw2[c5*3+0]; wdw[c5][2] = dw2[c5*3+1]; wdw[c5][3] = dw2[c5*3+2];
            wdw[c5][4] = 0.f;
        }
    }

    float acc[80];
#pragma unroll
    for (int k = 0; k < 80; k++) acc[k] = 0.f;
    int c0 = gu << 3;

#pragma unroll 1
    for (int p = 0; p < 4; p++) {
        int l0 = (p << 8) + (lane << 2);
        // flw for these 4 l's: scalar array, constant indices everywhere
        float fwv[10][4];
#pragma unroll
        for (int nn = 0; nn < 10; nn++) {
            int n = nn < 5 ? nn : nn - 5;
            int off = nn < 5 ? 0 : LL;
            float4 t4 = *(const float4*)(flw + n * (2*LL) + off + l0);
            fwv[nn][0] = t4.x; fwv[nn][1] = t4.y; fwv[nn][2] = t4.z; fwv[nn][3] = t4.w;
        }
        // src window: 3 aligned b128 reads per channel (conflict-free stride-4)
        float dv[5][4], sv[5][4];
#pragma unroll
        for (int c5 = 0; c5 < 5; c5++) {
            int i0 = l0 + 8;
            float4 xa = *(const float4*)&srcS[c5][i0 - 4];
            float4 xb = *(const float4*)&srcS[c5][i0];
            float4 xc = *(const float4*)&srcS[c5][i0 + 4];
            float xx[12] = {xa.x, xa.y, xa.z, xa.w, xb.x, xb.y, xb.z, xb.w, xc.x, xc.y, xc.z, xc.w};
            sv[c5][0] = xb.x; sv[c5][1] = xb.y; sv[c5][2] = xb.z; sv[c5][3] = xb.w;
            if (br == 0) {
#pragma unroll
                for (int q = 0; q < 4; q++)
                    dv[c5][q] = wdw[c5][0]*xx[q+2] + wdw[c5][1]*xx[q+3] + wdw[c5][2]*xx[q+4]
                              + wdw[c5][3]*xx[q+5] + wdw[c5][4]*xx[q+6];
            } else {
#pragma unroll
                for (int q = 0; q < 4; q++)
                    dv[c5][q] = wdw[c5][1]*xx[q+3] + wdw[c5][2]*xx[q+4] + wdw[c5][3]*xx[q+5];
            }
        }
        // 8 channels of this wave
#pragma unroll
        for (int ci = 0; ci < 8; ci++) {
            const float4 A  = *(const float4*)&constS[c0+ci][0];
            const float4 B2 = *(const float4*)&constS[c0+ci][4];
            const float4 R0 = *(const float4*)&constS[c0+ci][8];
            const float4 R1 = *(const float4*)&constS[c0+ci][12];
            float e[4];
#pragma unroll
            for (int q = 0; q < 4; q++) {
                float y = B2.y + A.x*dv[0][q] + A.y*dv[1][q] + A.z*dv[2][q]
                                + A.w*dv[3][q] + B2.x*dv[4][q];
                float r = B2.z + R0.x*sv[0][q] + R0.y*sv[1][q] + R0.z*sv[2][q]
                                + R0.w*sv[3][q] + R1.x*sv[4][q];
                e[q] = fmaxf(y, 0.f) * r;
            }
#pragma unroll
            for (int nn = 0; nn < 10; nn++) {
                acc[ci*10 + nn] += e[0]*fwv[nn][0] + e[1]*fwv[nn][1]
                                 + e[2]*fwv[nn][2] + e[3]*fwv[nn][3];
            }
        }
    }

    // ---- reduce acc over 64 lanes (DPP); lane 63 writes this wave's 8 S rows ----
#pragma unroll
    for (int k = 0; k < 80; k++) acc[k] = wave_sum(acc[k]);
    if (lane == 63) {
#pragma unroll
        for (int ci = 0; ci < 8; ci++) {
            int c = c0 + ci;
            *(float4*)&SLds[c][0] = make_float4(acc[ci*10+0], acc[ci*10+1], acc[ci*10+2], acc[ci*10+3]);
            *(float4*)&SLds[c][4] = make_float4(acc[ci*10+4], acc[ci*10+5], acc[ci*10+6], acc[ci*10+7]);
            *(float2*)&SLds[c][8] = make_float2(acc[ci*10+8], acc[ci*10+9]);
        }
    }
    __syncthreads();

    // ---- PQ[half][a][n] = sum_c llT[c][a] * S[c][half*5+n] + ll1b[a] * F[half*5+n] ----
    if (tid < 130) {
        int half = tid >= 65 ? 1 : 0;
        int q = tid - half * 65;
        int a = q / 5, n = q - a * 5;
        int col = half * 5 + n;
        float v = ll1b[a] * ws[WS_F + col];
#pragma unroll 8
        for (int cc = 0; cc < 64; cc++) v += llT[cc * 13 + a] * SLds[cc][col];
        PQ[tid] = v;
    }
    __syncthreads();

    // ---- out[b,i,j,n] = P[min,n] + Q[max,n] + flb[n] ----
    for (int idx = tid; idx < AA * AA * NBP; idx += 512) {
        int i = idx / 65;
        int rr = idx - i * 65;
        int j = rr / 5, n = rr - j * 5;
        int mn = i < j ? i : j, mx = i < j ? j : i;
        out[b * (AA * AA * NBP) + idx] = PQ[mn * 5 + n] + PQ[65 + mx * 5 + n] + flb[n];
    }
}

extern "C" void kernel_launch(void* const* d_in, const int* in_sizes, int n_in,
                              void* d_out, int out_size, void* d_ws, size_t ws_size,
                              hipStream_t stream) {
    const float* src  = (const float*)d_in[0];
    // d_in[1] = mask (unused), d_in[2] = max_atoms (unused, == 13)
    const float* dw1  = (const float*)d_in[3];
    const float* pw1  = (const float*)d_in[4];
    const float* g1   = (const float*)d_in[5];
    const float* be1  = (const float*)d_in[6];
    const float* r1w  = (const float*)d_in[7];
    const float* r1b  = (const float*)d_in[8];
    const float* dw2  = (const float*)d_in[9];
    const float* pw2  = (const float*)d_in[10];
    const float* g2   = (const float*)d_in[11];
    const float* be2  = (const float*)d_in[12];
    const float* r2w  = (const float*)d_in[13];
    const float* r2b  = (const float*)d_in[14];
    const float* ll1w = (const float*)d_in[15];
    const float* ll1b = (const float*)d_in[16];
    const float* flw  = (const float*)d_in[17];
    const float* flb  = (const float*)d_in[18];
    float* ws  = (float*)d_ws;
    float* out = (float*)d_out;

    k_moments<<<256, 256, 0, stream>>>(src, dw1, dw2, flw, ws);
    k_fused<<<BB, 512, 0, stream>>>(src, dw1, dw2, pw1, pw2, g1, be1, g2, be2,
                                    r1w, r2w, r1b, r2b, flw, ll1w, ll1b, flb, ws, out);
}

// Round 7
// 152.732 us; speedup vs baseline: 3.1567x; 1.7157x over previous
//
#include <hip/hip_runtime.h>
#include <hip/hip_bf16.h>

// Problem constants
#define BB 512
#define LL 1024
#define AA 13
#define NBP 5
#define NTOT (BB * LL)
#define EPSV 1e-5f

// ws layout (floats)
#define WS_F     192       // 10: F[nn] = sum over half-l of flw
#define WS_PART  256       // 256 blocks * 40 moment partials
#define WS_CONST 10496     // 64 channels * 16 packed consts (written by k_prep)

// ---- DPP wave64 sum: result valid in lane 63 (VALU pipe, no LDS) ----
template<int CTRL, int RM, bool BC>
__device__ __forceinline__ float dppadd(float v) {
    int t = __builtin_amdgcn_update_dpp(0, __float_as_int(v), CTRL, RM, 0xf, BC);
    return v + __int_as_float(t);
}
__device__ __forceinline__ float wave_sum(float v) {
    v = dppadd<0x111, 0xf, true >(v);   // row_shr:1
    v = dppadd<0x112, 0xf, true >(v);   // row_shr:2
    v = dppadd<0x114, 0xf, true >(v);   // row_shr:4
    v = dppadd<0x118, 0xf, true >(v);   // row_shr:8
    v = dppadd<0x142, 0xa, false>(v);   // row_bcast15
    v = dppadd<0x143, 0xc, false>(v);   // row_bcast31 -> lane63 total
    return v;
}

// ---------------- Kernel 1: depthwise-output moment partials + flw half-row sums ----------------
__global__ __launch_bounds__(256) void k_moments(
    const float* __restrict__ src,
    const float* __restrict__ dw1,
    const float* __restrict__ dw2,
    const float* __restrict__ flw,
    float* __restrict__ ws)
{
    __shared__ float red[4][40];
    __shared__ float fred[4];
    int tid = threadIdx.x;
    int gid = blockIdx.x * 256 + tid;
    int b = gid >> 7, L0 = (gid & 127) << 3;     // 8-wide strip per thread
    const float* sb = src + b * (5 * LL);

    float w1[5][5], w2[5][3];
#pragma unroll
    for (int c = 0; c < 5; c++) {
#pragma unroll
        for (int t = 0; t < 5; t++) w1[c][t] = dw1[c*5+t];
#pragma unroll
        for (int t = 0; t < 3; t++) w2[c][t] = dw2[c*3+t];
    }

    // x[c5][m] covers l = L0-4 .. L0+11
    float x[5][16];
#pragma unroll
    for (int c5 = 0; c5 < 5; c5++) {
        const float* sp = sb + c5 * LL;
        float4 xa = (L0 >= 4)    ? *(const float4*)(sp + L0 - 4) : make_float4(0,0,0,0);
        float4 xb = *(const float4*)(sp + L0);
        float4 xc = *(const float4*)(sp + L0 + 4);
        float4 xd = (L0 <= 1012) ? *(const float4*)(sp + L0 + 8) : make_float4(0,0,0,0);
        x[c5][0]=xa.x; x[c5][1]=xa.y; x[c5][2]=xa.z; x[c5][3]=xa.w;
        x[c5][4]=xb.x; x[c5][5]=xb.y; x[c5][6]=xb.z; x[c5][7]=xb.w;
        x[c5][8]=xc.x; x[c5][9]=xc.y; x[c5][10]=xc.z; x[c5][11]=xc.w;
        x[c5][12]=xd.x; x[c5][13]=xd.y; x[c5][14]=xd.z; x[c5][15]=xd.w;
    }

    float acc[40];
#pragma unroll
    for (int k = 0; k < 40; k++) acc[k] = 0.f;

#pragma unroll
    for (int k = 0; k < 8; k++) {              // l = L0 + k
        float d1[5], d2[5];
#pragma unroll
        for (int c5 = 0; c5 < 5; c5++) {
            d1[c5] = w1[c5][0]*x[c5][k+2] + w1[c5][1]*x[c5][k+3] + w1[c5][2]*x[c5][k+4]
                   + w1[c5][3]*x[c5][k+5] + w1[c5][4]*x[c5][k+6];
            d2[c5] = w2[c5][0]*x[c5][k+3] + w2[c5][1]*x[c5][k+4] + w2[c5][2]*x[c5][k+5];
        }
#pragma unroll
        for (int j = 0; j < 5; j++) { acc[j] += d1[j]; acc[20+j] += d2[j]; }
#pragma unroll
        for (int j = 0; j < 5; j++)
#pragma unroll
            for (int kk = j; kk < 5; kk++) {
                int idx = j*(11-j)/2 + (kk - j);
                acc[5+idx]  += d1[j]*d1[kk];
                acc[25+idx] += d2[j]*d2[kk];
            }
    }

    int lane = tid & 63, wv = tid >> 6;
#pragma unroll
    for (int k = 0; k < 40; k++) acc[k] = wave_sum(acc[k]);
    if (lane == 63) {
#pragma unroll
        for (int k = 0; k < 40; k++) red[wv][k] = acc[k];
    }
    __syncthreads();
    if (tid < 40) {
        ws[WS_PART + blockIdx.x * 40 + tid] =
            red[0][tid] + red[1][tid] + red[2][tid] + red[3][tid];
    }

    // F[nn] = sum of one flw half-row; blocks 0..9 own one row each
    if (blockIdx.x < 10) {
        int nn = blockIdx.x;
        int n = nn < 5 ? nn : nn - 5;
        int off = nn < 5 ? 0 : LL;
        float4 v = *(const float4*)(flw + n * (2*LL) + off + tid * 4);
        float s = wave_sum(v.x + v.y + v.z + v.w);
        if (lane == 63) fred[wv] = s;
        __syncthreads();
        if (tid == 0) ws[WS_F + nn] = fred[0] + fred[1] + fred[2] + fred[3];
    }
}

// ---------------- Kernel 2: reduce partials + BN finalize -> packed consts in GLOBAL ws ----------------
// Consts must live in global memory so k_fused can read them with wave-uniform s_load
// into SGPRs (round-4-proven allocation; LDS consts cost +16 in-loop VGPRs -> spill storm).
__global__ __launch_bounds__(320) void k_prep(
    float* __restrict__ ws,
    const float* __restrict__ pw1, const float* __restrict__ pw2,
    const float* __restrict__ g1,  const float* __restrict__ be1,
    const float* __restrict__ g2,  const float* __restrict__ be2,
    const float* __restrict__ r1w, const float* __restrict__ r2w,
    const float* __restrict__ r1b, const float* __restrict__ r2b)
{
    __shared__ float momS[40];
    int tid = threadIdx.x;
    // reduce 256 partials for each of 40 values (8 threads per value)
    {
        int k = tid >> 3, sub = tid & 7;
        float v = 0.f;
#pragma unroll 8
        for (int t2 = 0; t2 < 32; t2++) v += ws[WS_PART + (sub + (t2 << 3)) * 40 + k];
        v += __shfl_xor(v, 1, 64);
        v += __shfl_xor(v, 2, 64);
        v += __shfl_xor(v, 4, 64);
        if (sub == 0) momS[k] = v;
    }
    __syncthreads();
    if (tid < 64) {
        int brc = tid >> 5, o = tid & 31;
        const float invN = 1.0f / (float)NTOT;
        const float* pw = brc ? pw2 : pw1;
        const float* rw = brc ? r2w : r1w;
        const float* s  = momS + (brc ? 20 : 0);
        const float* M  = momS + (brc ? 25 : 5);
        float pwv[5], rwv[5], md[5];
#pragma unroll
        for (int j = 0; j < 5; j++) { pwv[j] = pw[o*5+j]; rwv[j] = rw[o*5+j]; md[j] = s[j] * invN; }
        float meanY = 0.f;
#pragma unroll
        for (int j = 0; j < 5; j++) meanY += pwv[j] * md[j];
        float ey2 = 0.f;
#pragma unroll
        for (int j = 0; j < 5; j++)
#pragma unroll
            for (int k = 0; k < 5; k++) {
                int lo = j < k ? j : k, hi = j < k ? k : j;
                int idx = lo*(11-lo)/2 + (hi - lo);
                ey2 += pwv[j] * pwv[k] * (M[idx] * invN);
            }
        float varY = ey2 - meanY * meanY;
        if (varY < 0.f) varY = 0.f;
        float gg = brc ? g2[o] : g1[o];
        float bb = brc ? be2[o] : be1[o];
        float rb = brc ? r2b[o] : r1b[o];
        float sc = gg * rsqrtf(varY + EPSV);
        float sh = bb - meanY * sc;
        float* dst = ws + WS_CONST + tid * 16;
        dst[0] = pwv[0]*sc; dst[1] = pwv[1]*sc; dst[2] = pwv[2]*sc; dst[3] = pwv[3]*sc;
        dst[4] = pwv[4]*sc; dst[5] = sh;        dst[6] = rb;        dst[7] = 0.f;
        dst[8] = rwv[0];    dst[9] = rwv[1];    dst[10] = rwv[2];   dst[11] = rwv[3];
        dst[12] = rwv[4];   dst[13] = 0.f;      dst[14] = 0.f;      dst[15] = 0.f;
    }
}

// ---------------- Kernel 3: main contraction + PQ + out ----------------
// __launch_bounds__ 2nd arg = min BLOCKS/CU on this toolchain (round-5 evidence:
// (512,4) -> 64-VGPR cap -> 1.2 GB spill). (512,2) = 128-VGPR cap, proven fit.
__global__ __launch_bounds__(512, 2) void k_fused(
    const float* __restrict__ src,
    const float* __restrict__ dw1,
    const float* __restrict__ dw2,
    const float* __restrict__ flw,
    const float* __restrict__ ll1w,
    const float* __restrict__ ll1b,
    const float* __restrict__ flb,
    const float* __restrict__ ws,
    float* __restrict__ out)
{
    __shared__ __align__(16) float srcS[5][1040];  // i = l + 8; halo zeros at i=4..7, 1032..1035
    __shared__ __align__(16) float SLds[64][12];
    __shared__ float llT[832];                     // ll1w transposed: [c*13 + a]
    __shared__ float PQ[130];

    int tid = threadIdx.x, b = blockIdx.x;
    int lane = tid & 63;
    int gu = __builtin_amdgcn_readfirstlane(tid >> 6);   // wave 0..7 (uniform)
    int br = gu >> 2;                                     // waves 0-3 branch1, 4-7 branch2

    const float* srcB = src + b * (5 * LL);

    // ---- stage src (whole L, 5 channels) ----
    for (int idx = tid; idx < 5 * 256; idx += 512) {
        int c5 = idx >> 8, q = idx & 255;
        float4 v = *(const float4*)(srcB + (c5 << 10) + (q << 2));
        *(float4*)&srcS[c5][(q << 2) + 8] = v;
    }
    if (tid < 40) {   // halo zeros: i = 4..7 and 1032..1035 per channel
        int c5 = tid >> 3, j = tid & 7;
        int i = (j < 4) ? (4 + j) : (1028 + j);
        srcS[c5][i] = 0.f;
    }
    // ---- stage ll1w transposed ----
    for (int idx = tid; idx < 832; idx += 512) {
        int cc = idx / 13, a = idx - cc * 13;
        llT[idx] = ll1w[a * 64 + cc];
    }
    __syncthreads();

    // ---- depthwise taps (wave-uniform -> scalar regs) ----
    float wdw[5][5];  // br1: 5 taps; br2: only [1..3] used
    if (br == 0) {
#pragma unroll
        for (int c5 = 0; c5 < 5; c5++)
#pragma unroll
            for (int t = 0; t < 5; t++) wdw[c5][t] = dw1[c5*5+t];
    } else {
#pragma unroll
        for (int c5 = 0; c5 < 5; c5++) {
            wdw[c5][0] = 0.f;
            wdw[c5][1] = dw2[c5*3+0]; wdw[c5][2] = dw2[c5*3+1]; wdw[c5][3] = dw2[c5*3+2];
            wdw[c5][4] = 0.f;
        }
    }
    // wave-uniform pointer to this wave's 8 channels of packed consts -> s_load (SGPRs)
    const float* cb = ws + WS_CONST + (gu << 7);

    float acc[80];
#pragma unroll
    for (int k = 0; k < 80; k++) acc[k] = 0.f;
    int c0 = gu << 3;

#pragma unroll 1
    for (int p = 0; p < 4; p++) {
        int l0 = (p << 8) + (lane << 2);
        // flw for these 4 l's: scalar array, constant indices everywhere
        float fwv[10][4];
#pragma unroll
        for (int nn = 0; nn < 10; nn++) {
            int n = nn < 5 ? nn : nn - 5;
            int off = nn < 5 ? 0 : LL;
            float4 t4 = *(const float4*)(flw + n * (2*LL) + off + l0);
            fwv[nn][0] = t4.x; fwv[nn][1] = t4.y; fwv[nn][2] = t4.z; fwv[nn][3] = t4.w;
        }
        // src window: 3 aligned b128 reads per channel (conflict-free stride-4)
        float dv[5][4], sv[5][4];
#pragma unroll
        for (int c5 = 0; c5 < 5; c5++) {
            int i0 = l0 + 8;
            float4 xa = *(const float4*)&srcS[c5][i0 - 4];
            float4 xb = *(const float4*)&srcS[c5][i0];
            float4 xc = *(const float4*)&srcS[c5][i0 + 4];
            float xx[12] = {xa.x, xa.y, xa.z, xa.w, xb.x, xb.y, xb.z, xb.w, xc.x, xc.y, xc.z, xc.w};
            sv[c5][0] = xb.x; sv[c5][1] = xb.y; sv[c5][2] = xb.z; sv[c5][3] = xb.w;
            if (br == 0) {
#pragma unroll
                for (int q = 0; q < 4; q++)
                    dv[c5][q] = wdw[c5][0]*xx[q+2] + wdw[c5][1]*xx[q+3] + wdw[c5][2]*xx[q+4]
                              + wdw[c5][3]*xx[q+5] + wdw[c5][4]*xx[q+6];
            } else {
#pragma unroll
                for (int q = 0; q < 4; q++)
                    dv[c5][q] = wdw[c5][1]*xx[q+3] + wdw[c5][2]*xx[q+4] + wdw[c5][3]*xx[q+5];
            }
        }
        // 8 channels of this wave: consts via wave-uniform scalar loads
#pragma unroll
        for (int ci = 0; ci < 8; ci++) {
            const float4 A  = *(const float4*)(cb + ci*16);      // a0..a3 (pw*sc)
            const float4 B2 = *(const float4*)(cb + ci*16 + 4);  // a4, sh, rb
            const float4 R0 = *(const float4*)(cb + ci*16 + 8);  // r0..r3
            const float4 R1 = *(const float4*)(cb + ci*16 + 12); // r4
            float e[4];
#pragma unroll
            for (int q = 0; q < 4; q++) {
                float y = B2.y + A.x*dv[0][q] + A.y*dv[1][q] + A.z*dv[2][q]
                                + A.w*dv[3][q] + B2.x*dv[4][q];
                float r = B2.z + R0.x*sv[0][q] + R0.y*sv[1][q] + R0.z*sv[2][q]
                                + R0.w*sv[3][q] + R1.x*sv[4][q];
                e[q] = fmaxf(y, 0.f) * r;
            }
#pragma unroll
            for (int nn = 0; nn < 10; nn++) {
                acc[ci*10 + nn] += e[0]*fwv[nn][0] + e[1]*fwv[nn][1]
                                 + e[2]*fwv[nn][2] + e[3]*fwv[nn][3];
            }
        }
    }

    // ---- reduce acc over 64 lanes (DPP); lane 63 writes this wave's 8 S rows ----
#pragma unroll
    for (int k = 0; k < 80; k++) acc[k] = wave_sum(acc[k]);
    if (lane == 63) {
#pragma unroll
        for (int ci = 0; ci < 8; ci++) {
            int c = c0 + ci;
            *(float4*)&SLds[c][0] = make_float4(acc[ci*10+0], acc[ci*10+1], acc[ci*10+2], acc[ci*10+3]);
            *(float4*)&SLds[c][4] = make_float4(acc[ci*10+4], acc[ci*10+5], acc[ci*10+6], acc[ci*10+7]);
            *(float2*)&SLds[c][8] = make_float2(acc[ci*10+8], acc[ci*10+9]);
        }
    }
    __syncthreads();

    // ---- PQ[half][a][n] = sum_c llT[c][a] * S[c][half*5+n] + ll1b[a] * F[half*5+n] ----
    if (tid < 130) {
        int half = tid >= 65 ? 1 : 0;
        int q = tid - half * 65;
        int a = q / 5, n = q - a * 5;
        int col = half * 5 + n;
        float v = ll1b[a] * ws[WS_F + col];
#pragma unroll 8
        for (int cc = 0; cc < 64; cc++) v += llT[cc * 13 + a] * SLds[cc][col];
        PQ[tid] = v;
    }
    __syncthreads();

    // ---- out[b,i,j,n] = P[min,n] + Q[max,n] + flb[n] ----
    for (int idx = tid; idx < AA * AA * NBP; idx += 512) {
        int i = idx / 65;
        int rr = idx - i * 65;
        int j = rr / 5, n = rr - j * 5;
        int mn = i < j ? i : j, mx = i < j ? j : i;
        out[b * (AA * AA * NBP) + idx] = PQ[mn * 5 + n] + PQ[65 + mx * 5 + n] + flb[n];
    }
}

extern "C" void kernel_launch(void* const* d_in, const int* in_sizes, int n_in,
                              void* d_out, int out_size, void* d_ws, size_t ws_size,
                              hipStream_t stream) {
    const float* src  = (const float*)d_in[0];
    // d_in[1] = mask (unused), d_in[2] = max_atoms (unused, == 13)
    const float* dw1  = (const float*)d_in[3];
    const float* pw1  = (const float*)d_in[4];
    const float* g1   = (const float*)d_in[5];
    const float* be1  = (const float*)d_in[6];
    const float* r1w  = (const float*)d_in[7];
    const float* r1b  = (const float*)d_in[8];
    const float* dw2  = (const float*)d_in[9];
    const float* pw2  = (const float*)d_in[10];
    const float* g2   = (const float*)d_in[11];
    const float* be2  = (const float*)d_in[12];
    const float* r2w  = (const float*)d_in[13];
    const float* r2b  = (const float*)d_in[14];
    const float* ll1w = (const float*)d_in[15];
    const float* ll1b = (const float*)d_in[16];
    const float* flw  = (const float*)d_in[17];
    const float* flb  = (const float*)d_in[18];
    float* ws  = (float*)d_ws;
    float* out = (float*)d_out;

    k_moments<<<256, 256, 0, stream>>>(src, dw1, dw2, flw, ws);
    k_prep<<<1, 320, 0, stream>>>(ws, pw1, pw2, g1, be1, g2, be2, r1w, r2w, r1b, r2b);
    k_fused<<<BB, 512, 0, stream>>>(src, dw1, dw2, flw, ll1w, ll1b, flb, ws, out);
}